// Round 9
// baseline (230.565 us; speedup 1.0000x reference)
//
#include <hip/hip_runtime.h>
#include <hip/hip_bf16.h>
#include <stdint.h>
#include <stddef.h>

#define B_   8
#define N_   256
#define H_   128
#define E_   128
#define INZ  256
#define BIGN 1000000.0f

typedef float f32x4 __attribute__((ext_vector_type(4)));
typedef short bf16x8 __attribute__((ext_vector_type(8)));

static __device__ __forceinline__ unsigned cvt2(float a, float b) {
    unsigned short ra = __builtin_bit_cast(unsigned short, __float2bfloat16(a));
    unsigned short rb = __builtin_bit_cast(unsigned short, __float2bfloat16(b));
    return (unsigned)ra | ((unsigned)rb << 16);
}

static __device__ __forceinline__ bf16x8 mk_frag(f32x4 lo, f32x4 h4) {
    union { unsigned u[4]; bf16x8 v; } r;
    r.u[0] = cvt2(lo.x, lo.y);
    r.u[1] = cvt2(lo.z, lo.w);
    r.u[2] = cvt2(h4.x, h4.y);
    r.u[3] = cvt2(h4.z, h4.w);
    return r.v;
}

// ---------------------------------------------------------------------------
// prep: msg1 = z@W1+b1 ; m2g = z@W2+b2+graph@Wg+bg ; zo1 = z@Wo1+bo1
// blocks 0..7 also produce We^T -> bf16, XOR-pre-swizzled (R1 layout):
//   weT[(n*128 + k) ^ ((n&7)<<3)] = bf16(We[k][n])
// ---------------------------------------------------------------------------
__global__ __launch_bounds__(256) void prep_kernel(
    const float* __restrict__ node, const float* __restrict__ hidden,
    const float* __restrict__ gf,
    const float* __restrict__ W1, const float* __restrict__ b1,
    const float* __restrict__ W2, const float* __restrict__ b2,
    const float* __restrict__ Wg, const float* __restrict__ bg,
    const float* __restrict__ Wo1, const float* __restrict__ bo1,
    const float* __restrict__ We,
    float* __restrict__ msg1, float* __restrict__ m2g,
    float* __restrict__ zo1, unsigned short* __restrict__ weT)
{
    __shared__ float zs[4][INZ];
    const int t  = threadIdx.x;
    const int r0 = blockIdx.x * 4;
    const int b  = r0 >> 8;

    for (int idx = t; idx < 4 * INZ; idx += 256) {
        int r = idx >> 8, k = idx & 255;
        int row = r0 + r;
        zs[r][k] = (k < H_) ? node[(size_t)row * H_ + k]
                            : hidden[(size_t)row * H_ + (k - H_)];
    }
    if (blockIdx.x < 8) {
        int e0 = blockIdx.x * 2048;
        for (int e = e0 + t; e < e0 + 2048; e += 256) {
            int n = e >> 7, k = e & 127;
            weT[(n * 128 + k) ^ ((n & 7) << 3)] =
                (unsigned short)__builtin_bit_cast(unsigned short,
                    __float2bfloat16(We[k * 128 + n]));
        }
    }
    __syncthreads();

    const int col = t & 127;
    const int rg  = t >> 7;
    float a1[2] = {0, 0}, a2[2] = {0, 0}, ao[2] = {0, 0};

#pragma unroll 4
    for (int k = 0; k < INZ; ++k) {
        float w1 = W1[k * 128 + col];
        float w2 = W2[k * 128 + col];
        float wo = Wo1[k * 128 + col];
#pragma unroll
        for (int rr = 0; rr < 2; ++rr) {
            float zv = zs[rg * 2 + rr][k];
            a1[rr] = fmaf(zv, w1, a1[rr]);
            a2[rr] = fmaf(zv, w2, a2[rr]);
            ao[rr] = fmaf(zv, wo, ao[rr]);
        }
    }
    float mg = bg[col];
#pragma unroll 4
    for (int g = 0; g < 128; ++g)
        mg = fmaf(gf[b * 128 + g], Wg[g * 128 + col], mg);

    const float bb1 = b1[col], bb2 = b2[col], bbo = bo1[col];
#pragma unroll
    for (int rr = 0; rr < 2; ++rr) {
        size_t row = (size_t)(r0 + rg * 2 + rr);
        msg1[row * 128 + col] = a1[rr] + bb1;
        m2g[row * 128 + col]  = a2[rr] + bb2 + mg;
        zo1[row * 128 + col]  = ao[rr] + bbo;
    }
}

// ---------------------------------------------------------------------------
// main (SPARSE): 1024 blocks x 4 waves; wave = one (j, i-half of 128).
// Active-i bitmask via 2x __ballot on adj column j; walk 16 set bits per
// chunk (uniform ctz loop). A rows = 16 ACTIVE edge rows, loaded directly
// global->VGPR (2-chunk prefetch pipeline, no loop barriers). B = WeT panel
// in LDS (XOR swizzle). Reads only ~50% of edge (~134MB, L3-resident on
// replay). rmax[8] per lane; partials -> redp[(b,j)][ih][128].
// ---------------------------------------------------------------------------
__global__ __launch_bounds__(256, 3) void pgn_main(
    const float* __restrict__ edge, const float* __restrict__ adj,
    const float* __restrict__ m2g, const unsigned short* __restrict__ weT,
    float* __restrict__ redp)
{
    __shared__ __align__(16) short blds[128 * 128];   // 32KB B panel

    const int t    = threadIdx.x;
    const int lane = t & 63, w = t >> 6;
    const int hi   = lane >> 4, c15 = lane & 15;
    const int task = blockIdx.x * 4 + w;
    const int ih   = task & 1;
    const int j    = (task >> 1) & 255;
    const int b    = task >> 9;
    const int ibase = ih * 128;

    // ---- stage B panel (pre-swizzled) ----
    {
        const uint4* ws = (const uint4*)weT;
        uint4* wd = (uint4*)blds;
#pragma unroll
        for (int q = 0; q < 8; ++q) wd[t + 256 * q] = ws[t + 256 * q];
    }
    __syncthreads();

    // ---- active-i bitmask for (b, j, i in [ibase, ibase+128)) ----
    const float* ac = adj + ((size_t)(b * N_ + ibase)) * N_ + j;
    unsigned long long m0 = __ballot(ac[(size_t)lane * N_] > 0.0f);
    unsigned long long m1 = __ballot(ac[(size_t)(lane + 64) * N_] > 0.0f);
    const int cnt = __popcll(m0) + __popcll(m1);

    const float* erow = edge + (((size_t)(b * N_ + ibase)) * N_ + j) * E_;
    const float* mrow = m2g + (size_t)(b * N_ + ibase) * 128;

    float rmax[8];
#pragma unroll
    for (int n = 0; n < 8; ++n) rmax[n] = -BIGN;

#define EXTRACT(MYIA, I0, I1, I2, I3)                                        \
    {   MYIA = 0; I0 = 0; I1 = 0; I2 = 0; I3 = 0;                            \
        _Pragma("unroll")                                                    \
        for (int r = 0; r < 16; ++r) {                                       \
            int ir = 0;                                                      \
            if (m0) { ir = __builtin_ctzll(m0); m0 &= m0 - 1; }              \
            else if (m1) { ir = 64 + __builtin_ctzll(m1); m1 &= m1 - 1; }    \
            if (r == c15) MYIA = ir;                                         \
            if ((r >> 2) == hi) {                                            \
                if ((r & 3) == 0) I0 = ir;                                   \
                else if ((r & 3) == 1) I1 = ir;                              \
                else if ((r & 3) == 2) I2 = ir;                              \
                else I3 = ir;                                                \
            }                                                                \
        }                                                                    \
    }

#define ISSUEA(PF, MYIA)                                                     \
    {   const float* ar_ = erow + (size_t)(MYIA) * (N_ * E_) + hi * 8;       \
        _Pragma("unroll")                                                    \
        for (int ks = 0; ks < 4; ++ks) {                                     \
            PF[2 * ks]     = *(const f32x4*)(ar_ + ks * 32);                 \
            PF[2 * ks + 1] = *(const f32x4*)(ar_ + ks * 32 + 4);             \
        }                                                                    \
    }

#define COMPUTE(PF, I0, I1, I2, I3, REM)                                     \
    {   f32x4 acc[8] = {};                                                   \
        _Pragma("unroll")                                                    \
        for (int ks = 0; ks < 4; ++ks) {                                     \
            bf16x8 af = mk_frag(PF[2 * ks], PF[2 * ks + 1]);                 \
            _Pragma("unroll")                                                \
            for (int n = 0; n < 8; ++n) {                                    \
                int ecol = n * 16 + c15;                                     \
                int ba = (ecol * 256 + ks * 64 + hi * 16) ^ ((ecol & 7) << 4);\
                bf16x8 bv = *(const bf16x8*)((const char*)blds + ba);        \
                acc[n] = __builtin_amdgcn_mfma_f32_16x16x32_bf16(            \
                    af, bv, acc[n], 0, 0, 0);                                \
            }                                                                \
        }                                                                    \
        _Pragma("unroll")                                                    \
        for (int n = 0; n < 8; ++n) {                                        \
            float v0 = acc[n][0] + mrow[(size_t)(I0) * 128 + n * 16 + c15];  \
            float v1 = acc[n][1] + mrow[(size_t)(I1) * 128 + n * 16 + c15];  \
            float v2 = acc[n][2] + mrow[(size_t)(I2) * 128 + n * 16 + c15];  \
            float v3 = acc[n][3] + mrow[(size_t)(I3) * 128 + n * 16 + c15];  \
            if (hi * 4 + 0 >= (REM)) v0 = -BIGN;                             \
            if (hi * 4 + 1 >= (REM)) v1 = -BIGN;                             \
            if (hi * 4 + 2 >= (REM)) v2 = -BIGN;                             \
            if (hi * 4 + 3 >= (REM)) v3 = -BIGN;                             \
            rmax[n] = fmaxf(rmax[n], fmaxf(fmaxf(v0, v1), fmaxf(v2, v3)));   \
        }                                                                    \
    }

    const int nch = (cnt + 15) >> 4;
    if (nch > 0) {
        int iaA, a0, a1, a2, a3, iaB, b0, b1, b2, b3;
        f32x4 pA[8], pB[8];
        EXTRACT(iaA, a0, a1, a2, a3);
        ISSUEA(pA, iaA);
        int ch = 0;
        while (true) {
            if (ch + 1 < nch) { EXTRACT(iaB, b0, b1, b2, b3); ISSUEA(pB, iaB); }
            COMPUTE(pA, a0, a1, a2, a3, cnt - ch * 16);
            if (++ch >= nch) break;
            if (ch + 1 < nch) { EXTRACT(iaA, a0, a1, a2, a3); ISSUEA(pA, iaA); }
            COMPUTE(pB, b0, b1, b2, b3, cnt - ch * 16);
            if (++ch >= nch) break;
        }
    }

    // ---- reduce across hi groups; lanes c15 hold col n*16+c15 ----
#pragma unroll
    for (int n = 0; n < 8; ++n) {
        float v = rmax[n];
        v = fmaxf(v, __shfl_xor(v, 16, 64));
        v = fmaxf(v, __shfl_xor(v, 32, 64));
        rmax[n] = v;
    }
    if (hi == 0) {
        float* rp = redp + ((size_t)(b * N_ + j) * 2 + ih) * 128;
#pragma unroll
        for (int n = 0; n < 8; ++n) rp[n * 16 + c15] = rmax[n];
    }
}

// ---------------------------------------------------------------------------
// finish: red = max over 2 i-halves (guard empty), out = relu(zo1 +
// (red+msg1+be)@Wo2 + bo2). 256 blocks x 256 threads, 8 rows/block.
// ---------------------------------------------------------------------------
__global__ __launch_bounds__(256) void finish_kernel(
    const float* __restrict__ redp, const float* __restrict__ msg1,
    const float* __restrict__ zo1, const float* __restrict__ be,
    const float* __restrict__ Wo2, const float* __restrict__ bo2,
    float* __restrict__ out)
{
    __shared__ float rb[8][128];
    const int t  = threadIdx.x;
    const int r0 = blockIdx.x * 8;

    for (int idx = t; idx < 1024; idx += 256) {
        int rr = idx >> 7, k = idx & 127;
        int r  = r0 + rr;
        float v = fmaxf(redp[(size_t)r * 256 + k], redp[(size_t)r * 256 + 128 + k]);
        // exact-reference handling of "no active sender": keep -1e6 bare
        rb[rr][k] = (v < -9.0e5f) ? v
                                  : v + msg1[(size_t)r * 128 + k] + be[k];
    }
    __syncthreads();

    const int col  = t & 127;
    const int half = t >> 7;
#pragma unroll
    for (int rx = 0; rx < 4; ++rx) {
        int rr = half * 4 + rx;
        size_t row = (size_t)(r0 + rr);
        float a = 0.0f;
#pragma unroll 8
        for (int k = 0; k < 128; ++k)
            a = fmaf(rb[rr][k], Wo2[k * 128 + col], a);
        float o = zo1[row * 128 + col] + bo2[col] + a;
        out[row * 128 + col] = fmaxf(o, 0.0f);
    }
}

extern "C" void kernel_launch(void* const* d_in, const int* in_sizes, int n_in,
                              void* d_out, int out_size, void* d_ws, size_t ws_size,
                              hipStream_t stream) {
    const float* node   = (const float*)d_in[0];
    const float* edge   = (const float*)d_in[1];
    const float* gf     = (const float*)d_in[2];
    const float* adj    = (const float*)d_in[3];
    const float* hidden = (const float*)d_in[4];
    const float* W1  = (const float*)d_in[5];
    const float* b1  = (const float*)d_in[6];
    const float* W2  = (const float*)d_in[7];
    const float* b2  = (const float*)d_in[8];
    const float* We  = (const float*)d_in[9];
    const float* be  = (const float*)d_in[10];
    const float* Wg  = (const float*)d_in[11];
    const float* bg  = (const float*)d_in[12];
    const float* Wo1 = (const float*)d_in[13];
    const float* bo1 = (const float*)d_in[14];
    const float* Wo2 = (const float*)d_in[15];
    const float* bo2 = (const float*)d_in[16];
    float* out = (float*)d_out;

    float* msg1 = (float*)d_ws;                                   // 1 MB
    float* m2g  = msg1 + 2048 * 128;                              // 1 MB
    float* zo1  = m2g + 2048 * 128;                               // 1 MB
    unsigned short* weT = (unsigned short*)(zo1 + 2048 * 128);    // 32 KB
    float* redp = (float*)((char*)weT + 128 * 128 * sizeof(unsigned short)); // 2 MB

    hipLaunchKernelGGL(prep_kernel, dim3(512), dim3(256), 0, stream,
                       node, hidden, gf, W1, b1, W2, b2, Wg, bg, Wo1, bo1, We,
                       msg1, m2g, zo1, weT);
    hipLaunchKernelGGL(pgn_main, dim3(1024), dim3(256), 0, stream,
                       edge, adj, m2g, weT, redp);
    hipLaunchKernelGGL(finish_kernel, dim3(256), dim3(256), 0, stream,
                       redp, msg1, zo1, be, Wo2, bo2, out);
}